// Round 14
// baseline (180.632 us; speedup 1.0000x reference)
//
#include <hip/hip_runtime.h>
#include <hip/hip_bf16.h>

#define BB 8
#define TT 4
#define NN 4096
#define UU 64
#define EE 65536
#define BN (BB*NN)   // 32768
#define CAP 64
#define NEG 0.2f

// ws layout (float offsets); hp/es/ed ping-pong by t parity.
// hp stored f16; slot u16.
#define OFF_XT   0                      // 12*BN  (t,f,row)
#define OFF_HP0  (12*BN)                // BN*64 f16 h' (region sized for f32; half used)
#define OFF_HP1  (OFF_HP0 + 64*BN)
#define OFF_ES0  (OFF_HP1 + 64*BN)     // BN
#define OFF_ES1  (OFF_ES0 + BN)
#define OFF_ED0  (OFF_ES1 + BN)
#define OFF_ED1  (OFF_ED0 + BN)
#define OFF_CNT  (OFF_ED1 + BN)        // NN ints
#define OFF_SLOT (OFF_CNT + NN)        // NN*CAP u16 (region sized for int; half used)
#define OFF_W    (OFF_SLOT + NN*CAP)   // f16 weight panels (frag-ordered)

// f16 panel offsets (in halfs).
#define PW1 0          // G1: [s|x|0](96) @ g1W -> 128 cols; 8n x 3kk
#define PW2 12288      // G2: [rs|x|0](96) @ g2W -> 64 cols; 4n x 3kk
#define PW3 18432      // G3: [h|x'|0](96) @ gW  -> 64 cols; 4n x 3kk
#define PW4 24576      // G4: h(64) @ oW -> 16 cols (3 used); 1n x 2kk
#define NPANEL 25600

// prologue sub-grid bounds (256-thr blocks)
#define PB_CONV 1536   // 12*BN/256
#define PB_FILL 272    // (EE+NN)/256
#define PB_PACK 100    // NPANEL/256 (exactly NPANEL threads)
#define PB_GAT  512    // BN/64 rows, 64 rows/block

typedef _Float16 f16_t;
typedef _Float16 f16x8 __attribute__((ext_vector_type(8)));
typedef float f32x4 __attribute__((ext_vector_type(4)));

// XCD-aware block remaps: pin batch i to XCD i (R2: FETCH 42.9->7.4 MB; keep).
// R10 lesson: kernel boundaries are the cheap sync on gfx950 (device-scope
// fence = L2 writeback-inv, ~100us).
__device__ __forceinline__ int xcd_remap(int bid) {     // grid 512
  return ((bid & 7) << 6) | (bid >> 3);
}
__device__ __forceinline__ int xcd_remap1k(int bid) {   // grid 1024
  return ((bid & 7) << 7) | (bid >> 3);
}

// readlane helpers: VALU broadcast -> SGPR.
__device__ __forceinline__ float rlf(float v, int l) {
  return __int_as_float(__builtin_amdgcn_readlane(__float_as_int(v), l));
}
__device__ __forceinline__ int rli(int v, int l) {
  return __builtin_amdgcn_readlane(v, l);
}

// prologue = conv_x | fill | wpack | gat0 (mutually independent ranges).
__global__ __launch_bounds__(256) void k_prolog(const float* x, const int* src,
                                                const int* dst, const float* g1W,
                                                const float* g2W, const float* gW,
                                                const float* oW, const float* as_,
                                                const float* ad_, float* ws) {
  int bid = blockIdx.x;
  int tid = threadIdx.x;
  if (bid < PB_CONV) {
    // transpose x -> xT[(t,f,row)]
    int i = bid * 256 + tid;
    int r = i & (BN - 1);
    int tf = i >> 15;
    int t = tf / 3, f = tf - 3 * t;
    int b = r >> 12, n = r & (NN - 1);
    ws[OFF_XT + i] = x[(((b * TT + t) * NN + n) * 3) + f];
  } else if (bid < PB_CONV + PB_FILL) {
    // slot fill (cnt memset'd before this kernel)
    int* cnt = (int*)(ws + OFF_CNT);
    unsigned short* slot = (unsigned short*)(ws + OFF_SLOT);
    int i = (bid - PB_CONV) * 256 + tid;
    if (i < EE) {
      int d = dst[i];
      int p = atomicAdd(&cnt[d], 1);
      if (p < CAP) slot[d * CAP + p] = (unsigned short)src[i];
    } else {
      int n = i - EE;
      int p = atomicAdd(&cnt[n], 1);
      if (p < CAP) slot[n * CAP + p] = (unsigned short)n;
    }
  } else if (bid < PB_CONV + PB_FILL + PB_PACK) {
    // pack f32 weights into frag-ordered f16 panels
    f16_t* P = (f16_t*)(ws + OFF_W);
    int i = (bid - PB_CONV - PB_FILL) * 256 + tid;
    int j = i & 7;
    int l = (i >> 3) & 63;
    int kap = ((l >> 4) << 3) + j;
    float v = 0.f;
    if (i < PW2) {
      int r = i >> 9;
      int kk = r % 3, n = r / 3;
      int k = kk * 32 + kap, col = n * 16 + (l & 15);
      if (k < 64) v = g1W[(3 + k) * 128 + col];
      else if (k < 67) v = g1W[(k - 64) * 128 + col];
    } else if (i < PW3) {
      int r = (i - PW2) >> 9;
      int kk = r % 3, n = r / 3;
      int k = kk * 32 + kap, col = n * 16 + (l & 15);
      if (k < 64) v = g2W[(3 + k) * 64 + col];
      else if (k < 67) v = g2W[(k - 64) * 64 + col];
    } else if (i < PW4) {
      int r = (i - PW3) >> 9;
      int kk = r % 3, n = r / 3;
      int k = kk * 32 + kap, col = n * 16 + (l & 15);
      if (k < 67) v = gW[k * 64 + col];
    } else {
      int kk = (i - PW4) >> 9;
      int k = kk * 32 + kap, col = l & 15;
      if (col < 3) v = oW[k * 3 + col];
    }
    P[i] = (f16_t)v;
  } else {
    // ---- GAT0 (t=0, h=0): h' = x_0 @ gat_W[64:67]; es/ed; f16 hp0 ----
    f16_t* hp = (f16_t*)(ws + OFF_HP0);
    float* es = ws + OFF_ES0;
    float* ed = ws + OFF_ED0;
    int wave = __builtin_amdgcn_readfirstlane(tid >> 6);  // 0..3
    int lane = tid & 63;
    int lb = xcd_remap(bid - PB_CONV - PB_FILL - PB_PACK);
    int row = lb * 64 + lane;
    int b = row >> 12, n = row & (NN - 1);
    int u0 = wave * 16;
    float xv[3];
#pragma unroll
    for (int k = 0; k < 3; ++k)
      xv[k] = x[((size_t)(b * TT) * NN + n) * 3 + k];   // t=0 slice
    float acc[16];
#pragma unroll
    for (int j = 0; j < 16; ++j) acc[j] = 0.f;
#pragma unroll
    for (int k = 0; k < 3; ++k) {
      float ck = xv[k];
#pragma unroll
      for (int j = 0; j < 16; ++j) acc[j] += ck * gW[(64 + k) * 64 + u0 + j];
    }
    float esa = 0.f, eda = 0.f;
#pragma unroll
    for (int j = 0; j < 16; ++j) {
      esa += acc[j] * as_[u0 + j];
      eda += acc[j] * ad_[u0 + j];
    }
    f16x8 o0, o1;
#pragma unroll
    for (int j = 0; j < 8; ++j) { o0[j] = (f16_t)acc[j]; o1[j] = (f16_t)acc[8 + j]; }
    *(f16x8*)(hp + (size_t)row * 64 + u0) = o0;
    *(f16x8*)(hp + (size_t)row * 64 + u0 + 8) = o1;
    __shared__ float esL[4][64], edL[4][64];
    esL[wave][lane] = esa;
    edL[wave][lane] = eda;
    __syncthreads();
    if (wave == 0) {
      float s = 0.f;
#pragma unroll
      for (int w = 0; w < 4; ++w) s += esL[w][lane];
      es[row] = s;
    } else if (wave == 1) {
      float s = 0.f;
#pragma unroll
      for (int w = 0; w < 4; ++w) s += edL[w][lane];
      ed[row] = s;
    }
  }
}

// R14 k_step: as R13 (32 rows/block, grid 1024, 100% occupancy) with P1's
// weighted gather interleaved across ALL 4 rows (32 loads in flight, one
// latency window instead of two). Per-row sum order unchanged (bitwise-same).
__global__ __launch_bounds__(512, 8) void k_step(
    float* ws, const f16_t* P, const float* gb, const float* g1b,
    const float* g2b, const float* as_, const float* ad_,
    const float* ob, float* out, int t, int last) {
  const float* xT = ws + OFF_XT;
  int pr = t & 1;
  const f16_t* hpR = (const f16_t*)(ws + (pr ? OFF_HP1 : OFF_HP0));
  const float* esR = ws + (pr ? OFF_ES1 : OFF_ES0);
  const float* edR = ws + (pr ? OFF_ED1 : OFF_ED0);
  f16_t* hpW = (f16_t*)(ws + (pr ? OFF_HP0 : OFF_HP1));
  float* esW = ws + (pr ? OFF_ES0 : OFF_ES1);
  float* edW = ws + (pr ? OFF_ED0 : OFF_ED1);
  const int* cnt = (const int*)(ws + OFF_CNT);
  const unsigned short* slot = (const unsigned short*)(ws + OFF_SLOT);

  int tid = threadIdx.x;
  int wave = __builtin_amdgcn_readfirstlane(tid >> 6);  // 0..7
  int lane = tid & 63;
  int lb = xcd_remap1k(blockIdx.x);
  int rowbase = lb * 32;
  int b = rowbase >> 12;
  int nbase = rowbase & (NN - 1);
  int r0 = wave * 4;

  __shared__ f16_t sx[32][104];    // A-tile: [s|x|0] -> later [h|x'|0]
  __shared__ f16_t rsx[32][104];   // A-tile: [r*s|x|0]
  __shared__ f16_t ugx[32][64];    // u gate
  __shared__ float peL[4][32], pdL[4][32];

  // tail fill k=64..95 of sx,rsx = [x(t) | zeros]
  for (int i = tid; i < 32 * 32; i += 512) {
    int row = i >> 5, kq = i & 31;
    f16_t v = (f16_t)0.f;
    if (kq < 3) v = (f16_t)xT[(t * 3 + kq) * BN + rowbase + row];
    sx[row][64 + kq] = v;
    rsx[row][64 + kq] = v;
  }

  float gbv = gb[lane];   // lane = u in P1

  // ---- P1 (pipelined): batch scalar loads for 4 rows ----
  int deg4[4]; float ed4[4];
#pragma unroll
  for (int rr = 0; rr < 4; ++rr) {
    int n = nbase + r0 + rr;
    deg4[rr] = min(cnt[n], CAP);
    ed4[rr] = edR[b * NN + n];
  }
  int sl4[4];
#pragma unroll
  for (int rr = 0; rr < 4; ++rr) {
    int n = nbase + r0 + rr;
    int sv = (int)slot[n * CAP + lane];
    sl4[rr] = (lane < deg4[rr]) ? sv : 0;   // masked -> row 0 (finite), w=0
  }
  float w4[4];
#pragma unroll
  for (int rr = 0; rr < 4; ++rr) {
    float ev = esR[b * NN + sl4[rr]];       // 4 gathers in flight
    float e = (lane < deg4[rr]) ? (ev + ed4[rr]) : -1e30f;
    e = e > 0.f ? e : NEG * e;              // -1e30 -> exp underflows to 0
    w4[rr] = __expf(e);
  }
#pragma unroll
  for (int rr = 0; rr < 4; ++rr) {
    float dsum = w4[rr];
#pragma unroll
    for (int o = 32; o >= 1; o >>= 1) dsum += __shfl_xor(dsum, o, 64);
    w4[rr] *= 1.f / dsum;
  }
  // weighted gather, ALL 4 rows interleaved (32 loads in flight)
  const f16_t* hpB = hpR + (size_t)b * NN * 64;
  {
    float ac0 = 0.f, ac1 = 0.f, ac2 = 0.f, ac3 = 0.f;
    int dm = max(max(deg4[0], deg4[1]), max(deg4[2], deg4[3]));
#pragma unroll 1
    for (int i0 = 0; i0 < dm; i0 += 8) {
      float v0[8], v1[8], v2[8], v3[8];
#pragma unroll
      for (int j = 0; j < 8; ++j) {
        v0[j] = (float)hpB[(size_t)rli(sl4[0], i0 + j) * 64 + lane];
        v1[j] = (float)hpB[(size_t)rli(sl4[1], i0 + j) * 64 + lane];
        v2[j] = (float)hpB[(size_t)rli(sl4[2], i0 + j) * 64 + lane];
        v3[j] = (float)hpB[(size_t)rli(sl4[3], i0 + j) * 64 + lane];
      }
#pragma unroll
      for (int j = 0; j < 8; ++j) {
        ac0 += rlf(w4[0], i0 + j) * v0[j];   // w==0 beyond deg
        ac1 += rlf(w4[1], i0 + j) * v1[j];
        ac2 += rlf(w4[2], i0 + j) * v2[j];
        ac3 += rlf(w4[3], i0 + j) * v3[j];
      }
    }
    sx[r0 + 0][lane] = (f16_t)(ac0 + gbv);
    sx[r0 + 1][lane] = (f16_t)(ac1 + gbv);
    sx[r0 + 2][lane] = (f16_t)(ac2 + gbv);
    sx[r0 + 3][lane] = (f16_t)(ac3 + gbv);
  }
  __syncthreads();

  const f16x8* W1v = (const f16x8*)(P + PW1);
  const f16x8* W2v = (const f16x8*)(P + PW2);
  const f16x8* W3v = (const f16x8*)(P + PW3);
  const f16x8* W4v = (const f16x8*)(P + PW4);

  int m = wave >> 2;               // C row-tile (0..1)
  int q = wave & 3;
  int col16 = lane & 15;
  int g4 = (lane >> 4) << 2;       // C row-group offset within tile
  int rbase = m * 16 + g4;         // + j = local row
  int afrow = m * 16 + col16;      // A-frag row (row = lane&15)
  int afk = (lane >> 4) << 3;      // A-frag k offset within kk-step

  // ---- G1: [s|x] @ g1W -> 32x128 (r | u pre-activations), 2 tiles/wave ----
  int nb1 = q * 2;                 // col-tiles nb1, nb1+1 (0..7)
  f32x4 acc1[2] = {{0,0,0,0},{0,0,0,0}};
#pragma unroll
  for (int kk = 0; kk < 3; ++kk) {
    f16x8 a = *(const f16x8*)&sx[afrow][kk * 32 + afk];
#pragma unroll
    for (int nt = 0; nt < 2; ++nt) {
      f16x8 bf = W1v[((nb1 + nt) * 3 + kk) * 64 + lane];
      acc1[nt] = __builtin_amdgcn_mfma_f32_16x16x32_f16(a, bf, acc1[nt], 0, 0, 0);
    }
  }
  if (q < 2) {                     // r half: col-tiles 0..3 -> rs -> rsx
#pragma unroll
    for (int nt = 0; nt < 2; ++nt) {
      int colR = (nb1 + nt) * 16 + col16;
      float bR = g1b[colR];
#pragma unroll
      for (int j = 0; j < 4; ++j) {
        int row = rbase + j;
        float rg = 1.f / (1.f + __expf(-(acc1[nt][j] + bR)));
        rsx[row][colR] = (f16_t)(rg * (float)sx[row][colR]);
      }
    }
  } else {                          // u half: col-tiles 4..7 -> ug -> ugx
#pragma unroll
    for (int nt = 0; nt < 2; ++nt) {
      int colU = (nb1 - 4 + nt) * 16 + col16;
      float bU = g1b[64 + colU];
#pragma unroll
      for (int j = 0; j < 4; ++j) {
        int row = rbase + j;
        float ug = 1.f / (1.f + __expf(-(acc1[nt][j] + bU)));
        ugx[row][colU] = (f16_t)ug;
      }
    }
  }
  __syncthreads();

  // ---- G2: [rs|x] @ g2W -> candidate; h update; 1 tile/wave ----
  f32x4 acc2 = {0, 0, 0, 0};
#pragma unroll
  for (int kk = 0; kk < 3; ++kk) {
    f16x8 a = *(const f16x8*)&rsx[afrow][kk * 32 + afk];
    f16x8 bf = W2v[(q * 3 + kk) * 64 + lane];
    acc2 = __builtin_amdgcn_mfma_f32_16x16x32_f16(a, bf, acc2, 0, 0, 0);
  }
  {
    int col = q * 16 + col16;
    float bC = g2b[col];
#pragma unroll
    for (int j = 0; j < 4; ++j) {
      int row = rbase + j;
      float z = acc2[j] + bC;
      float c = 1.f - 2.f / (__expf(2.f * z) + 1.f);
      float ug = (float)ugx[row][col];
      float sv = (float)sx[row][col];
      sx[row][col] = (f16_t)(ug * sv + (1.f - ug) * c);   // h (owner-only RMW)
    }
  }
  if (!last && tid < 128) {        // x(t) -> x(t+1) in sx tail
    int row = tid >> 2, k3 = tid & 3;
    if (k3 < 3)
      sx[row][64 + k3] = (f16_t)xT[((t + 1) * 3 + k3) * BN + rowbase + row];
  }
  __syncthreads();

  if (!last) {
    // ---- G3: [h|x'] @ gat_W -> hp' (f16) + es/ed; 1 tile/wave ----
    f32x4 acc3 = {0, 0, 0, 0};
#pragma unroll
    for (int kk = 0; kk < 3; ++kk) {
      f16x8 a = *(const f16x8*)&sx[afrow][kk * 32 + afk];
      f16x8 bf = W3v[(q * 3 + kk) * 64 + lane];
      acc3 = __builtin_amdgcn_mfma_f32_16x16x32_f16(a, bf, acc3, 0, 0, 0);
    }
    int col = q * 16 + col16;
    float asv = as_[col], adv = ad_[col];
    float pe[4], pd[4];
#pragma unroll
    for (int j = 0; j < 4; ++j) {
      int row = rbase + j;
      float aG = acc3[j];
      hpW[(size_t)(rowbase + row) * 64 + col] = (f16_t)aG;
      pe[j] = aG * asv;
      pd[j] = aG * adv;
    }
#pragma unroll
    for (int j = 0; j < 4; ++j) {
#pragma unroll
      for (int o = 1; o < 16; o <<= 1) {
        pe[j] += __shfl_xor(pe[j], o, 64);
        pd[j] += __shfl_xor(pd[j], o, 64);
      }
    }
    if (col16 == 0) {
#pragma unroll
      for (int j = 0; j < 4; ++j) {
        peL[q][rbase + j] = pe[j];
        pdL[q][rbase + j] = pd[j];
      }
    }
    __syncthreads();
    if (tid < 32) {
      esW[rowbase + tid] = peL[0][tid] + peL[1][tid] + peL[2][tid] + peL[3][tid];
    } else if (tid < 64) {
      int r_ = tid - 32;
      edW[rowbase + r_] = pdL[0][r_] + pdL[1][r_] + pdL[2][r_] + pdL[3][r_];
    }
  } else {
    // ---- G4: out = h @ oW + ob (waves 0 and 4; 1 M-tile each) ----
    if (q == 0) {
      f32x4 acc4 = {0, 0, 0, 0};
#pragma unroll
      for (int kk = 0; kk < 2; ++kk) {
        f16x8 a = *(const f16x8*)&sx[m * 16 + col16][kk * 32 + afk];
        f16x8 bf = W4v[kk * 64 + lane];
        acc4 = __builtin_amdgcn_mfma_f32_16x16x32_f16(a, bf, acc4, 0, 0, 0);
      }
      if (col16 < 3) {
        float obv = ob[col16];
#pragma unroll
        for (int j = 0; j < 4; ++j) {
          int row = m * 16 + g4 + j;
          out[(size_t)(rowbase + row) * 3 + col16] = acc4[j] + obv;
        }
      }
    }
  }
}

extern "C" void kernel_launch(void* const* d_in, const int* in_sizes, int n_in,
                              void* d_out, int out_size, void* d_ws, size_t ws_size,
                              hipStream_t stream) {
  const float* x = (const float*)d_in[0];
  const int* src = (const int*)d_in[1];
  const int* dst = (const int*)d_in[2];
  const float* gatW = (const float*)d_in[3];
  const float* asrc = (const float*)d_in[4];
  const float* adst = (const float*)d_in[5];
  const float* gatb = (const float*)d_in[6];
  const float* g1W = (const float*)d_in[7];
  const float* g1b = (const float*)d_in[8];
  const float* g2W = (const float*)d_in[9];
  const float* g2b = (const float*)d_in[10];
  const float* oW = (const float*)d_in[11];
  const float* ob = (const float*)d_in[12];
  float* ws = (float*)d_ws;
  float* out = (float*)d_out;
  f16_t* P = (f16_t*)(ws + OFF_W);

  hipMemsetAsync(ws + OFF_CNT, 0, NN * sizeof(int), stream);
  k_prolog<<<PB_CONV + PB_FILL + PB_PACK + PB_GAT, 256, 0, stream>>>(
      x, src, dst, g1W, g2W, gatW, oW, asrc, adst, ws);
  for (int t = 0; t < TT; ++t) {
    k_step<<<BN / 32, 512, 0, stream>>>(ws, P, gatb, g1b, g2b, asrc, adst,
                                        ob, out, t, t == TT - 1 ? 1 : 0);
  }
}

// Round 15
// 174.689 us; speedup vs baseline: 1.0340x; 1.0340x over previous
//
#include <hip/hip_runtime.h>
#include <hip/hip_bf16.h>

#define BB 8
#define TT 4
#define NN 4096
#define UU 64
#define EE 65536
#define BN (BB*NN)   // 32768
#define CAP 64
#define NEG 0.2f

// ws layout (float offsets); hp/es/ed ping-pong by t parity.
// hp stored f16; slot u16.
#define OFF_XT   0                      // 12*BN  (t,f,row)
#define OFF_HP0  (12*BN)                // BN*64 f16 h' (region sized for f32; half used)
#define OFF_HP1  (OFF_HP0 + 64*BN)
#define OFF_ES0  (OFF_HP1 + 64*BN)     // BN
#define OFF_ES1  (OFF_ES0 + BN)
#define OFF_ED0  (OFF_ES1 + BN)
#define OFF_ED1  (OFF_ED0 + BN)
#define OFF_CNT  (OFF_ED1 + BN)        // NN ints
#define OFF_SLOT (OFF_CNT + NN)        // NN*CAP u16 (region sized for int; half used)
#define OFF_W    (OFF_SLOT + NN*CAP)   // f16 weight panels (frag-ordered)

// f16 panel offsets (in halfs).
#define PW1 0          // G1: [s|x|0](96) @ g1W -> 128 cols; 8n x 3kk
#define PW2 12288      // G2: [rs|x|0](96) @ g2W -> 64 cols; 4n x 3kk
#define PW3 18432      // G3: [h|x'|0](96) @ gW  -> 64 cols; 4n x 3kk
#define PW4 24576      // G4: h(64) @ oW -> 16 cols (3 used); 1n x 2kk
#define NPANEL 25600

// prologue sub-grid bounds (256-thr blocks)
#define PB_CONV 1536   // 12*BN/256
#define PB_FILL 272    // (EE+NN)/256
#define PB_PACK 100    // NPANEL/256 (exactly NPANEL threads)
#define PB_GAT  512    // BN/64 rows, 64 rows/block

typedef _Float16 f16_t;
typedef _Float16 f16x8 __attribute__((ext_vector_type(8)));
typedef float f32x4 __attribute__((ext_vector_type(4)));

// XCD-aware block remaps: pin batch i to XCD i (R2: FETCH 42.9->7.4 MB; keep).
// R10 lesson: kernel boundaries are the cheap sync on gfx950 (device-scope
// fence = L2 writeback-inv, ~100us).
// R14 lesson: 4-row gather interleave regresses (+5us) -- VGPR pressure at
// the 64-reg cap; 2-row (16 loads in flight) is the sweet spot at 100% occ.
__device__ __forceinline__ int xcd_remap(int bid) {     // grid 512
  return ((bid & 7) << 6) | (bid >> 3);
}
__device__ __forceinline__ int xcd_remap1k(int bid) {   // grid 1024
  return ((bid & 7) << 7) | (bid >> 3);
}

// readlane helpers: VALU broadcast -> SGPR.
__device__ __forceinline__ float rlf(float v, int l) {
  return __int_as_float(__builtin_amdgcn_readlane(__float_as_int(v), l));
}
__device__ __forceinline__ int rli(int v, int l) {
  return __builtin_amdgcn_readlane(v, l);
}

// prologue = conv_x | fill | wpack | gat0 (mutually independent ranges).
__global__ __launch_bounds__(256) void k_prolog(const float* x, const int* src,
                                                const int* dst, const float* g1W,
                                                const float* g2W, const float* gW,
                                                const float* oW, const float* as_,
                                                const float* ad_, float* ws) {
  int bid = blockIdx.x;
  int tid = threadIdx.x;
  if (bid < PB_CONV) {
    // transpose x -> xT[(t,f,row)]
    int i = bid * 256 + tid;
    int r = i & (BN - 1);
    int tf = i >> 15;
    int t = tf / 3, f = tf - 3 * t;
    int b = r >> 12, n = r & (NN - 1);
    ws[OFF_XT + i] = x[(((b * TT + t) * NN + n) * 3) + f];
  } else if (bid < PB_CONV + PB_FILL) {
    // slot fill (cnt memset'd before this kernel)
    int* cnt = (int*)(ws + OFF_CNT);
    unsigned short* slot = (unsigned short*)(ws + OFF_SLOT);
    int i = (bid - PB_CONV) * 256 + tid;
    if (i < EE) {
      int d = dst[i];
      int p = atomicAdd(&cnt[d], 1);
      if (p < CAP) slot[d * CAP + p] = (unsigned short)src[i];
    } else {
      int n = i - EE;
      int p = atomicAdd(&cnt[n], 1);
      if (p < CAP) slot[n * CAP + p] = (unsigned short)n;
    }
  } else if (bid < PB_CONV + PB_FILL + PB_PACK) {
    // pack f32 weights into frag-ordered f16 panels
    f16_t* P = (f16_t*)(ws + OFF_W);
    int i = (bid - PB_CONV - PB_FILL) * 256 + tid;
    int j = i & 7;
    int l = (i >> 3) & 63;
    int kap = ((l >> 4) << 3) + j;
    float v = 0.f;
    if (i < PW2) {
      int r = i >> 9;
      int kk = r % 3, n = r / 3;
      int k = kk * 32 + kap, col = n * 16 + (l & 15);
      if (k < 64) v = g1W[(3 + k) * 128 + col];
      else if (k < 67) v = g1W[(k - 64) * 128 + col];
    } else if (i < PW3) {
      int r = (i - PW2) >> 9;
      int kk = r % 3, n = r / 3;
      int k = kk * 32 + kap, col = n * 16 + (l & 15);
      if (k < 64) v = g2W[(3 + k) * 64 + col];
      else if (k < 67) v = g2W[(k - 64) * 64 + col];
    } else if (i < PW4) {
      int r = (i - PW3) >> 9;
      int kk = r % 3, n = r / 3;
      int k = kk * 32 + kap, col = n * 16 + (l & 15);
      if (k < 67) v = gW[k * 64 + col];
    } else {
      int kk = (i - PW4) >> 9;
      int k = kk * 32 + kap, col = l & 15;
      if (col < 3) v = oW[k * 3 + col];
    }
    P[i] = (f16_t)v;
  } else {
    // ---- GAT0 (t=0, h=0): h' = x_0 @ gat_W[64:67]; es/ed; f16 hp0 ----
    f16_t* hp = (f16_t*)(ws + OFF_HP0);
    float* es = ws + OFF_ES0;
    float* ed = ws + OFF_ED0;
    int wave = __builtin_amdgcn_readfirstlane(tid >> 6);  // 0..3
    int lane = tid & 63;
    int lb = xcd_remap(bid - PB_CONV - PB_FILL - PB_PACK);
    int row = lb * 64 + lane;
    int b = row >> 12, n = row & (NN - 1);
    int u0 = wave * 16;
    float xv[3];
#pragma unroll
    for (int k = 0; k < 3; ++k)
      xv[k] = x[((size_t)(b * TT) * NN + n) * 3 + k];   // t=0 slice
    float acc[16];
#pragma unroll
    for (int j = 0; j < 16; ++j) acc[j] = 0.f;
#pragma unroll
    for (int k = 0; k < 3; ++k) {
      float ck = xv[k];
#pragma unroll
      for (int j = 0; j < 16; ++j) acc[j] += ck * gW[(64 + k) * 64 + u0 + j];
    }
    float esa = 0.f, eda = 0.f;
#pragma unroll
    for (int j = 0; j < 16; ++j) {
      esa += acc[j] * as_[u0 + j];
      eda += acc[j] * ad_[u0 + j];
    }
    f16x8 o0, o1;
#pragma unroll
    for (int j = 0; j < 8; ++j) { o0[j] = (f16_t)acc[j]; o1[j] = (f16_t)acc[8 + j]; }
    *(f16x8*)(hp + (size_t)row * 64 + u0) = o0;
    *(f16x8*)(hp + (size_t)row * 64 + u0 + 8) = o1;
    __shared__ float esL[4][64], edL[4][64];
    esL[wave][lane] = esa;
    edL[wave][lane] = eda;
    __syncthreads();
    if (wave == 0) {
      float s = 0.f;
#pragma unroll
      for (int w = 0; w < 4; ++w) s += esL[w][lane];
      es[row] = s;
    } else if (wave == 1) {
      float s = 0.f;
#pragma unroll
      for (int w = 0; w < 4; ++w) s += edL[w][lane];
      ed[row] = s;
    }
  }
}

// R13 k_step (best measured: 175.5us total): 32 rows/block, grid 1024,
// 512 thr, 4 blocks/CU = 100% occupancy. P1 = 4 rows/wave with 2-row
// gather interleave (16 loads in flight); G1 = 2 tiles; G2/G3 = 1 tile.
__global__ __launch_bounds__(512, 8) void k_step(
    float* ws, const f16_t* P, const float* gb, const float* g1b,
    const float* g2b, const float* as_, const float* ad_,
    const float* ob, float* out, int t, int last) {
  const float* xT = ws + OFF_XT;
  int pr = t & 1;
  const f16_t* hpR = (const f16_t*)(ws + (pr ? OFF_HP1 : OFF_HP0));
  const float* esR = ws + (pr ? OFF_ES1 : OFF_ES0);
  const float* edR = ws + (pr ? OFF_ED1 : OFF_ED0);
  f16_t* hpW = (f16_t*)(ws + (pr ? OFF_HP0 : OFF_HP1));
  float* esW = ws + (pr ? OFF_ES0 : OFF_ES1);
  float* edW = ws + (pr ? OFF_ED0 : OFF_ED1);
  const int* cnt = (const int*)(ws + OFF_CNT);
  const unsigned short* slot = (const unsigned short*)(ws + OFF_SLOT);

  int tid = threadIdx.x;
  int wave = __builtin_amdgcn_readfirstlane(tid >> 6);  // 0..7
  int lane = tid & 63;
  int lb = xcd_remap1k(blockIdx.x);
  int rowbase = lb * 32;
  int b = rowbase >> 12;
  int nbase = rowbase & (NN - 1);
  int r0 = wave * 4;

  __shared__ f16_t sx[32][104];    // A-tile: [s|x|0] -> later [h|x'|0]
  __shared__ f16_t rsx[32][104];   // A-tile: [r*s|x|0]
  __shared__ f16_t ugx[32][64];    // u gate
  __shared__ float peL[4][32], pdL[4][32];

  // tail fill k=64..95 of sx,rsx = [x(t) | zeros]
  for (int i = tid; i < 32 * 32; i += 512) {
    int row = i >> 5, kq = i & 31;
    f16_t v = (f16_t)0.f;
    if (kq < 3) v = (f16_t)xT[(t * 3 + kq) * BN + rowbase + row];
    sx[row][64 + kq] = v;
    rsx[row][64 + kq] = v;
  }

  float gbv = gb[lane];   // lane = u in P1

  // ---- P1 (pipelined): batch scalar loads for 4 rows ----
  int deg4[4]; float ed4[4];
#pragma unroll
  for (int rr = 0; rr < 4; ++rr) {
    int n = nbase + r0 + rr;
    deg4[rr] = min(cnt[n], CAP);
    ed4[rr] = edR[b * NN + n];
  }
  int sl4[4];
#pragma unroll
  for (int rr = 0; rr < 4; ++rr) {
    int n = nbase + r0 + rr;
    int sv = (int)slot[n * CAP + lane];
    sl4[rr] = (lane < deg4[rr]) ? sv : 0;   // masked -> row 0 (finite), w=0
  }
  float w4[4];
#pragma unroll
  for (int rr = 0; rr < 4; ++rr) {
    float ev = esR[b * NN + sl4[rr]];       // 4 gathers in flight
    float e = (lane < deg4[rr]) ? (ev + ed4[rr]) : -1e30f;
    e = e > 0.f ? e : NEG * e;              // -1e30 -> exp underflows to 0
    w4[rr] = __expf(e);
  }
#pragma unroll
  for (int rr = 0; rr < 4; ++rr) {
    float dsum = w4[rr];
#pragma unroll
    for (int o = 32; o >= 1; o >>= 1) dsum += __shfl_xor(dsum, o, 64);
    w4[rr] *= 1.f / dsum;
  }
  // weighted gather, 2 rows interleaved (16 loads in flight)
  const f16_t* hpB = hpR + (size_t)b * NN * 64;
#pragma unroll
  for (int rp = 0; rp < 4; rp += 2) {
    float accA = 0.f, accB = 0.f;
    int dA = deg4[rp], dB = deg4[rp + 1];
    int dm = dA > dB ? dA : dB;
#pragma unroll 1
    for (int i0 = 0; i0 < dm; i0 += 8) {
      float vA[8], vB[8];
#pragma unroll
      for (int j = 0; j < 8; ++j) {
        vA[j] = (float)hpB[(size_t)rli(sl4[rp], i0 + j) * 64 + lane];
        vB[j] = (float)hpB[(size_t)rli(sl4[rp + 1], i0 + j) * 64 + lane];
      }
#pragma unroll
      for (int j = 0; j < 8; ++j) {
        accA += rlf(w4[rp], i0 + j) * vA[j];     // w==0 beyond deg
        accB += rlf(w4[rp + 1], i0 + j) * vB[j];
      }
    }
    sx[r0 + rp][lane] = (f16_t)(accA + gbv);
    sx[r0 + rp + 1][lane] = (f16_t)(accB + gbv);
  }
  __syncthreads();

  const f16x8* W1v = (const f16x8*)(P + PW1);
  const f16x8* W2v = (const f16x8*)(P + PW2);
  const f16x8* W3v = (const f16x8*)(P + PW3);
  const f16x8* W4v = (const f16x8*)(P + PW4);

  int m = wave >> 2;               // C row-tile (0..1)
  int q = wave & 3;
  int col16 = lane & 15;
  int g4 = (lane >> 4) << 2;       // C row-group offset within tile
  int rbase = m * 16 + g4;         // + j = local row
  int afrow = m * 16 + col16;      // A-frag row (row = lane&15)
  int afk = (lane >> 4) << 3;      // A-frag k offset within kk-step

  // ---- G1: [s|x] @ g1W -> 32x128 (r | u pre-activations), 2 tiles/wave ----
  int nb1 = q * 2;                 // col-tiles nb1, nb1+1 (0..7)
  f32x4 acc1[2] = {{0,0,0,0},{0,0,0,0}};
#pragma unroll
  for (int kk = 0; kk < 3; ++kk) {
    f16x8 a = *(const f16x8*)&sx[afrow][kk * 32 + afk];
#pragma unroll
    for (int nt = 0; nt < 2; ++nt) {
      f16x8 bf = W1v[((nb1 + nt) * 3 + kk) * 64 + lane];
      acc1[nt] = __builtin_amdgcn_mfma_f32_16x16x32_f16(a, bf, acc1[nt], 0, 0, 0);
    }
  }
  if (q < 2) {                     // r half: col-tiles 0..3 -> rs -> rsx
#pragma unroll
    for (int nt = 0; nt < 2; ++nt) {
      int colR = (nb1 + nt) * 16 + col16;
      float bR = g1b[colR];
#pragma unroll
      for (int j = 0; j < 4; ++j) {
        int row = rbase + j;
        float rg = 1.f / (1.f + __expf(-(acc1[nt][j] + bR)));
        rsx[row][colR] = (f16_t)(rg * (float)sx[row][colR]);
      }
    }
  } else {                          // u half: col-tiles 4..7 -> ug -> ugx
#pragma unroll
    for (int nt = 0; nt < 2; ++nt) {
      int colU = (nb1 - 4 + nt) * 16 + col16;
      float bU = g1b[64 + colU];
#pragma unroll
      for (int j = 0; j < 4; ++j) {
        int row = rbase + j;
        float ug = 1.f / (1.f + __expf(-(acc1[nt][j] + bU)));
        ugx[row][colU] = (f16_t)ug;
      }
    }
  }
  __syncthreads();

  // ---- G2: [rs|x] @ g2W -> candidate; h update; 1 tile/wave ----
  f32x4 acc2 = {0, 0, 0, 0};
#pragma unroll
  for (int kk = 0; kk < 3; ++kk) {
    f16x8 a = *(const f16x8*)&rsx[afrow][kk * 32 + afk];
    f16x8 bf = W2v[(q * 3 + kk) * 64 + lane];
    acc2 = __builtin_amdgcn_mfma_f32_16x16x32_f16(a, bf, acc2, 0, 0, 0);
  }
  {
    int col = q * 16 + col16;
    float bC = g2b[col];
#pragma unroll
    for (int j = 0; j < 4; ++j) {
      int row = rbase + j;
      float z = acc2[j] + bC;
      float c = 1.f - 2.f / (__expf(2.f * z) + 1.f);
      float ug = (float)ugx[row][col];
      float sv = (float)sx[row][col];
      sx[row][col] = (f16_t)(ug * sv + (1.f - ug) * c);   // h (owner-only RMW)
    }
  }
  if (!last && tid < 128) {        // x(t) -> x(t+1) in sx tail
    int row = tid >> 2, k3 = tid & 3;
    if (k3 < 3)
      sx[row][64 + k3] = (f16_t)xT[((t + 1) * 3 + k3) * BN + rowbase + row];
  }
  __syncthreads();

  if (!last) {
    // ---- G3: [h|x'] @ gat_W -> hp' (f16) + es/ed; 1 tile/wave ----
    f32x4 acc3 = {0, 0, 0, 0};
#pragma unroll
    for (int kk = 0; kk < 3; ++kk) {
      f16x8 a = *(const f16x8*)&sx[afrow][kk * 32 + afk];
      f16x8 bf = W3v[(q * 3 + kk) * 64 + lane];
      acc3 = __builtin_amdgcn_mfma_f32_16x16x32_f16(a, bf, acc3, 0, 0, 0);
    }
    int col = q * 16 + col16;
    float asv = as_[col], adv = ad_[col];
    float pe[4], pd[4];
#pragma unroll
    for (int j = 0; j < 4; ++j) {
      int row = rbase + j;
      float aG = acc3[j];
      hpW[(size_t)(rowbase + row) * 64 + col] = (f16_t)aG;
      pe[j] = aG * asv;
      pd[j] = aG * adv;
    }
#pragma unroll
    for (int j = 0; j < 4; ++j) {
#pragma unroll
      for (int o = 1; o < 16; o <<= 1) {
        pe[j] += __shfl_xor(pe[j], o, 64);
        pd[j] += __shfl_xor(pd[j], o, 64);
      }
    }
    if (col16 == 0) {
#pragma unroll
      for (int j = 0; j < 4; ++j) {
        peL[q][rbase + j] = pe[j];
        pdL[q][rbase + j] = pd[j];
      }
    }
    __syncthreads();
    if (tid < 32) {
      esW[rowbase + tid] = peL[0][tid] + peL[1][tid] + peL[2][tid] + peL[3][tid];
    } else if (tid < 64) {
      int r_ = tid - 32;
      edW[rowbase + r_] = pdL[0][r_] + pdL[1][r_] + pdL[2][r_] + pdL[3][r_];
    }
  } else {
    // ---- G4: out = h @ oW + ob (waves 0 and 4; 1 M-tile each) ----
    if (q == 0) {
      f32x4 acc4 = {0, 0, 0, 0};
#pragma unroll
      for (int kk = 0; kk < 2; ++kk) {
        f16x8 a = *(const f16x8*)&sx[m * 16 + col16][kk * 32 + afk];
        f16x8 bf = W4v[kk * 64 + lane];
        acc4 = __builtin_amdgcn_mfma_f32_16x16x32_f16(a, bf, acc4, 0, 0, 0);
      }
      if (col16 < 3) {
        float obv = ob[col16];
#pragma unroll
        for (int j = 0; j < 4; ++j) {
          int row = m * 16 + g4 + j;
          out[(size_t)(rowbase + row) * 3 + col16] = acc4[j] + obv;
        }
      }
    }
  }
}

extern "C" void kernel_launch(void* const* d_in, const int* in_sizes, int n_in,
                              void* d_out, int out_size, void* d_ws, size_t ws_size,
                              hipStream_t stream) {
  const float* x = (const float*)d_in[0];
  const int* src = (const int*)d_in[1];
  const int* dst = (const int*)d_in[2];
  const float* gatW = (const float*)d_in[3];
  const float* asrc = (const float*)d_in[4];
  const float* adst = (const float*)d_in[5];
  const float* gatb = (const float*)d_in[6];
  const float* g1W = (const float*)d_in[7];
  const float* g1b = (const float*)d_in[8];
  const float* g2W = (const float*)d_in[9];
  const float* g2b = (const float*)d_in[10];
  const float* oW = (const float*)d_in[11];
  const float* ob = (const float*)d_in[12];
  float* ws = (float*)d_ws;
  float* out = (float*)d_out;
  f16_t* P = (f16_t*)(ws + OFF_W);

  hipMemsetAsync(ws + OFF_CNT, 0, NN * sizeof(int), stream);
  k_prolog<<<PB_CONV + PB_FILL + PB_PACK + PB_GAT, 256, 0, stream>>>(
      x, src, dst, g1W, g2W, gatW, oW, asrc, adst, ws);
  for (int t = 0; t < TT; ++t) {
    k_step<<<BN / 32, 512, 0, stream>>>(ws, P, gatb, g1b, g2b, asrc, adst,
                                        ob, out, t, t == TT - 1 ? 1 : 0);
  }
}

// Round 16
// 173.199 us; speedup vs baseline: 1.0429x; 1.0086x over previous
//
#include <hip/hip_runtime.h>
#include <hip/hip_bf16.h>

#define BB 8
#define TT 4
#define NN 4096
#define UU 64
#define EE 65536
#define BN (BB*NN)   // 32768
#define CAP 64
#define NEG 0.2f

// ws layout (float offsets); hp/es/ed ping-pong by t parity.
// hp stored f16; slot u16.
#define OFF_XT   0                      // 12*BN  (t,f,row)
#define OFF_HP0  (12*BN)                // BN*64 f16 h' (region sized for f32; half used)
#define OFF_HP1  (OFF_HP0 + 64*BN)
#define OFF_ES0  (OFF_HP1 + 64*BN)     // BN
#define OFF_ES1  (OFF_ES0 + BN)
#define OFF_ED0  (OFF_ES1 + BN)
#define OFF_ED1  (OFF_ED0 + BN)
#define OFF_CNT  (OFF_ED1 + BN)        // NN ints
#define OFF_SLOT (OFF_CNT + NN)        // NN*CAP u16 (region sized for int; half used)
#define OFF_W    (OFF_SLOT + NN*CAP)   // f16 weight panels (frag-ordered)

// f16 panel offsets (in halfs).
#define PW1 0          // G1: [s|x|0](96) @ g1W -> 128 cols; 8n x 3kk
#define PW2 12288      // G2: [rs|x|0](96) @ g2W -> 64 cols; 4n x 3kk
#define PW3 18432      // G3: [h|x'|0](96) @ gW  -> 64 cols; 4n x 3kk
#define PW4 24576      // G4: h(64) @ oW -> 16 cols (3 used); 1n x 2kk
#define NPANEL 25600

// prologue sub-grid bounds (256-thr blocks)
#define PB_CONV 1536   // 12*BN/256
#define PB_FILL 272    // (EE+NN)/256
#define PB_PACK 100    // NPANEL/256 (exactly NPANEL threads)
#define PB_GAT  512    // BN/64 rows, 64 rows/block

typedef _Float16 f16_t;
typedef _Float16 f16x8 __attribute__((ext_vector_type(8)));
typedef float f32x4 __attribute__((ext_vector_type(4)));

// XCD-aware block remaps: pin batch i to XCD i (R2: FETCH 42.9->7.4 MB; keep).
// R10 lesson: kernel boundaries are the cheap sync on gfx950 (device-scope
// fence = L2 writeback-inv, ~100us).
// R14 lesson: 4-row gather interleave regresses (+5us) -- VGPR pressure at
// the 64-reg cap; 2-row (16 loads in flight) is the sweet spot at 100% occ.
__device__ __forceinline__ int xcd_remap(int bid) {     // grid 512
  return ((bid & 7) << 6) | (bid >> 3);
}
__device__ __forceinline__ int xcd_remap1k(int bid) {   // grid 1024
  return ((bid & 7) << 7) | (bid >> 3);
}

// readlane helpers: VALU broadcast -> SGPR.
__device__ __forceinline__ float rlf(float v, int l) {
  return __int_as_float(__builtin_amdgcn_readlane(__float_as_int(v), l));
}
__device__ __forceinline__ int rli(int v, int l) {
  return __builtin_amdgcn_readlane(v, l);
}

// prologue = conv_x | fill | wpack | gat0 (mutually independent ranges).
__global__ __launch_bounds__(256) void k_prolog(const float* x, const int* src,
                                                const int* dst, const float* g1W,
                                                const float* g2W, const float* gW,
                                                const float* oW, const float* as_,
                                                const float* ad_, float* ws) {
  int bid = blockIdx.x;
  int tid = threadIdx.x;
  if (bid < PB_CONV) {
    // transpose x -> xT[(t,f,row)]
    int i = bid * 256 + tid;
    int r = i & (BN - 1);
    int tf = i >> 15;
    int t = tf / 3, f = tf - 3 * t;
    int b = r >> 12, n = r & (NN - 1);
    ws[OFF_XT + i] = x[(((b * TT + t) * NN + n) * 3) + f];
  } else if (bid < PB_CONV + PB_FILL) {
    // slot fill (cnt memset'd before this kernel)
    int* cnt = (int*)(ws + OFF_CNT);
    unsigned short* slot = (unsigned short*)(ws + OFF_SLOT);
    int i = (bid - PB_CONV) * 256 + tid;
    if (i < EE) {
      int d = dst[i];
      int p = atomicAdd(&cnt[d], 1);
      if (p < CAP) slot[d * CAP + p] = (unsigned short)src[i];
    } else {
      int n = i - EE;
      int p = atomicAdd(&cnt[n], 1);
      if (p < CAP) slot[n * CAP + p] = (unsigned short)n;
    }
  } else if (bid < PB_CONV + PB_FILL + PB_PACK) {
    // pack f32 weights into frag-ordered f16 panels
    f16_t* P = (f16_t*)(ws + OFF_W);
    int i = (bid - PB_CONV - PB_FILL) * 256 + tid;
    int j = i & 7;
    int l = (i >> 3) & 63;
    int kap = ((l >> 4) << 3) + j;
    float v = 0.f;
    if (i < PW2) {
      int r = i >> 9;
      int kk = r % 3, n = r / 3;
      int k = kk * 32 + kap, col = n * 16 + (l & 15);
      if (k < 64) v = g1W[(3 + k) * 128 + col];
      else if (k < 67) v = g1W[(k - 64) * 128 + col];
    } else if (i < PW3) {
      int r = (i - PW2) >> 9;
      int kk = r % 3, n = r / 3;
      int k = kk * 32 + kap, col = n * 16 + (l & 15);
      if (k < 64) v = g2W[(3 + k) * 64 + col];
      else if (k < 67) v = g2W[(k - 64) * 64 + col];
    } else if (i < PW4) {
      int r = (i - PW3) >> 9;
      int kk = r % 3, n = r / 3;
      int k = kk * 32 + kap, col = n * 16 + (l & 15);
      if (k < 67) v = gW[k * 64 + col];
    } else {
      int kk = (i - PW4) >> 9;
      int k = kk * 32 + kap, col = l & 15;
      if (col < 3) v = oW[k * 3 + col];
    }
    P[i] = (f16_t)v;
  } else {
    // ---- GAT0 (t=0, h=0): h' = x_0 @ gat_W[64:67]; es/ed; f16 hp0 ----
    f16_t* hp = (f16_t*)(ws + OFF_HP0);
    float* es = ws + OFF_ES0;
    float* ed = ws + OFF_ED0;
    int wave = __builtin_amdgcn_readfirstlane(tid >> 6);  // 0..3
    int lane = tid & 63;
    int lb = xcd_remap(bid - PB_CONV - PB_FILL - PB_PACK);
    int row = lb * 64 + lane;
    int b = row >> 12, n = row & (NN - 1);
    int u0 = wave * 16;
    float xv[3];
#pragma unroll
    for (int k = 0; k < 3; ++k)
      xv[k] = x[((size_t)(b * TT) * NN + n) * 3 + k];   // t=0 slice
    float acc[16];
#pragma unroll
    for (int j = 0; j < 16; ++j) acc[j] = 0.f;
#pragma unroll
    for (int k = 0; k < 3; ++k) {
      float ck = xv[k];
#pragma unroll
      for (int j = 0; j < 16; ++j) acc[j] += ck * gW[(64 + k) * 64 + u0 + j];
    }
    float esa = 0.f, eda = 0.f;
#pragma unroll
    for (int j = 0; j < 16; ++j) {
      esa += acc[j] * as_[u0 + j];
      eda += acc[j] * ad_[u0 + j];
    }
    f16x8 o0, o1;
#pragma unroll
    for (int j = 0; j < 8; ++j) { o0[j] = (f16_t)acc[j]; o1[j] = (f16_t)acc[8 + j]; }
    *(f16x8*)(hp + (size_t)row * 64 + u0) = o0;
    *(f16x8*)(hp + (size_t)row * 64 + u0 + 8) = o1;
    __shared__ float esL[4][64], edL[4][64];
    esL[wave][lane] = esa;
    edL[wave][lane] = eda;
    __syncthreads();
    if (wave == 0) {
      float s = 0.f;
#pragma unroll
      for (int w = 0; w < 4; ++w) s += esL[w][lane];
      es[row] = s;
    } else if (wave == 1) {
      float s = 0.f;
#pragma unroll
      for (int w = 0; w < 4; ++w) s += edL[w][lane];
      ed[row] = s;
    }
  }
}

// R16 k_step: as R13 (32 rows/block, grid 1024, 100% occupancy, 2-row gather
// interleave) with G1 re-partitioned: wave (m,q) computes its r-tile (m,q)
// -> rsx AND its u-tile (m,4+q) -> REGISTERS (same C-fragment layout as its
// G2 tile), deleting the ugx LDS round-trip. Same MFMA tiles, same inputs
// -> bitwise-identical output.
__global__ __launch_bounds__(512, 8) void k_step(
    float* ws, const f16_t* P, const float* gb, const float* g1b,
    const float* g2b, const float* as_, const float* ad_,
    const float* ob, float* out, int t, int last) {
  const float* xT = ws + OFF_XT;
  int pr = t & 1;
  const f16_t* hpR = (const f16_t*)(ws + (pr ? OFF_HP1 : OFF_HP0));
  const float* esR = ws + (pr ? OFF_ES1 : OFF_ES0);
  const float* edR = ws + (pr ? OFF_ED1 : OFF_ED0);
  f16_t* hpW = (f16_t*)(ws + (pr ? OFF_HP0 : OFF_HP1));
  float* esW = ws + (pr ? OFF_ES0 : OFF_ES1);
  float* edW = ws + (pr ? OFF_ED0 : OFF_ED1);
  const int* cnt = (const int*)(ws + OFF_CNT);
  const unsigned short* slot = (const unsigned short*)(ws + OFF_SLOT);

  int tid = threadIdx.x;
  int wave = __builtin_amdgcn_readfirstlane(tid >> 6);  // 0..7
  int lane = tid & 63;
  int lb = xcd_remap1k(blockIdx.x);
  int rowbase = lb * 32;
  int b = rowbase >> 12;
  int nbase = rowbase & (NN - 1);
  int r0 = wave * 4;

  __shared__ f16_t sx[32][104];    // A-tile: [s|x|0] -> later [h|x'|0]
  __shared__ f16_t rsx[32][104];   // A-tile: [r*s|x|0]
  __shared__ float peL[4][32], pdL[4][32];

  // tail fill k=64..95 of sx,rsx = [x(t) | zeros]
  for (int i = tid; i < 32 * 32; i += 512) {
    int row = i >> 5, kq = i & 31;
    f16_t v = (f16_t)0.f;
    if (kq < 3) v = (f16_t)xT[(t * 3 + kq) * BN + rowbase + row];
    sx[row][64 + kq] = v;
    rsx[row][64 + kq] = v;
  }

  float gbv = gb[lane];   // lane = u in P1

  // ---- P1 (pipelined): batch scalar loads for 4 rows ----
  int deg4[4]; float ed4[4];
#pragma unroll
  for (int rr = 0; rr < 4; ++rr) {
    int n = nbase + r0 + rr;
    deg4[rr] = min(cnt[n], CAP);
    ed4[rr] = edR[b * NN + n];
  }
  int sl4[4];
#pragma unroll
  for (int rr = 0; rr < 4; ++rr) {
    int n = nbase + r0 + rr;
    int sv = (int)slot[n * CAP + lane];
    sl4[rr] = (lane < deg4[rr]) ? sv : 0;   // masked -> row 0 (finite), w=0
  }
  float w4[4];
#pragma unroll
  for (int rr = 0; rr < 4; ++rr) {
    float ev = esR[b * NN + sl4[rr]];       // 4 gathers in flight
    float e = (lane < deg4[rr]) ? (ev + ed4[rr]) : -1e30f;
    e = e > 0.f ? e : NEG * e;              // -1e30 -> exp underflows to 0
    w4[rr] = __expf(e);
  }
#pragma unroll
  for (int rr = 0; rr < 4; ++rr) {
    float dsum = w4[rr];
#pragma unroll
    for (int o = 32; o >= 1; o >>= 1) dsum += __shfl_xor(dsum, o, 64);
    w4[rr] *= 1.f / dsum;
  }
  // weighted gather, 2 rows interleaved (16 loads in flight)
  const f16_t* hpB = hpR + (size_t)b * NN * 64;
#pragma unroll
  for (int rp = 0; rp < 4; rp += 2) {
    float accA = 0.f, accB = 0.f;
    int dA = deg4[rp], dB = deg4[rp + 1];
    int dm = dA > dB ? dA : dB;
#pragma unroll 1
    for (int i0 = 0; i0 < dm; i0 += 8) {
      float vA[8], vB[8];
#pragma unroll
      for (int j = 0; j < 8; ++j) {
        vA[j] = (float)hpB[(size_t)rli(sl4[rp], i0 + j) * 64 + lane];
        vB[j] = (float)hpB[(size_t)rli(sl4[rp + 1], i0 + j) * 64 + lane];
      }
#pragma unroll
      for (int j = 0; j < 8; ++j) {
        accA += rlf(w4[rp], i0 + j) * vA[j];     // w==0 beyond deg
        accB += rlf(w4[rp + 1], i0 + j) * vB[j];
      }
    }
    sx[r0 + rp][lane] = (f16_t)(accA + gbv);
    sx[r0 + rp + 1][lane] = (f16_t)(accB + gbv);
  }
  __syncthreads();

  const f16x8* W1v = (const f16x8*)(P + PW1);
  const f16x8* W2v = (const f16x8*)(P + PW2);
  const f16x8* W3v = (const f16x8*)(P + PW3);
  const f16x8* W4v = (const f16x8*)(P + PW4);

  int m = wave >> 2;               // C row-tile (0..1)
  int q = wave & 3;
  int col16 = lane & 15;
  int g4 = (lane >> 4) << 2;       // C row-group offset within tile
  int rbase = m * 16 + g4;         // + j = local row
  int afrow = m * 16 + col16;      // A-frag row (row = lane&15)
  int afk = (lane >> 4) << 3;      // A-frag k offset within kk-step
  int col = q * 16 + col16;        // this wave's output column (G2/G3 tile q)

  // ---- G1: [s|x] @ g1W: wave (m,q) does r-tile (m,q) + u-tile (m,4+q) ----
  f32x4 accR = {0,0,0,0}, accU = {0,0,0,0};
#pragma unroll
  for (int kk = 0; kk < 3; ++kk) {
    f16x8 a = *(const f16x8*)&sx[afrow][kk * 32 + afk];
    f16x8 bR_ = W1v[(q * 3 + kk) * 64 + lane];
    f16x8 bU_ = W1v[((4 + q) * 3 + kk) * 64 + lane];
    accR = __builtin_amdgcn_mfma_f32_16x16x32_f16(a, bR_, accR, 0, 0, 0);
    accU = __builtin_amdgcn_mfma_f32_16x16x32_f16(a, bU_, accU, 0, 0, 0);
  }
  float ug4[4];
  {
    float bR = g1b[col];
    float bU = g1b[64 + col];
#pragma unroll
    for (int j = 0; j < 4; ++j) {
      int row = rbase + j;
      float rg = 1.f / (1.f + __expf(-(accR[j] + bR)));
      rsx[row][col] = (f16_t)(rg * (float)sx[row][col]);
      ug4[j] = 1.f / (1.f + __expf(-(accU[j] + bU)));   // u stays in regs
    }
  }
  __syncthreads();

  // ---- G2: [rs|x] @ g2W -> candidate; h update; 1 tile/wave ----
  f32x4 acc2 = {0, 0, 0, 0};
#pragma unroll
  for (int kk = 0; kk < 3; ++kk) {
    f16x8 a = *(const f16x8*)&rsx[afrow][kk * 32 + afk];
    f16x8 bf = W2v[(q * 3 + kk) * 64 + lane];
    acc2 = __builtin_amdgcn_mfma_f32_16x16x32_f16(a, bf, acc2, 0, 0, 0);
  }
  {
    float bC = g2b[col];
#pragma unroll
    for (int j = 0; j < 4; ++j) {
      int row = rbase + j;
      float z = acc2[j] + bC;
      float c = 1.f - 2.f / (__expf(2.f * z) + 1.f);
      float ug = ug4[j];
      float sv = (float)sx[row][col];
      sx[row][col] = (f16_t)(ug * sv + (1.f - ug) * c);   // h (owner-only RMW)
    }
  }
  if (!last && tid < 128) {        // x(t) -> x(t+1) in sx tail
    int row = tid >> 2, k3 = tid & 3;
    if (k3 < 3)
      sx[row][64 + k3] = (f16_t)xT[((t + 1) * 3 + k3) * BN + rowbase + row];
  }
  __syncthreads();

  if (!last) {
    // ---- G3: [h|x'] @ gat_W -> hp' (f16) + es/ed; 1 tile/wave ----
    f32x4 acc3 = {0, 0, 0, 0};
#pragma unroll
    for (int kk = 0; kk < 3; ++kk) {
      f16x8 a = *(const f16x8*)&sx[afrow][kk * 32 + afk];
      f16x8 bf = W3v[(q * 3 + kk) * 64 + lane];
      acc3 = __builtin_amdgcn_mfma_f32_16x16x32_f16(a, bf, acc3, 0, 0, 0);
    }
    float asv = as_[col], adv = ad_[col];
    float pe[4], pd[4];
#pragma unroll
    for (int j = 0; j < 4; ++j) {
      int row = rbase + j;
      float aG = acc3[j];
      hpW[(size_t)(rowbase + row) * 64 + col] = (f16_t)aG;
      pe[j] = aG * asv;
      pd[j] = aG * adv;
    }
#pragma unroll
    for (int j = 0; j < 4; ++j) {
#pragma unroll
      for (int o = 1; o < 16; o <<= 1) {
        pe[j] += __shfl_xor(pe[j], o, 64);
        pd[j] += __shfl_xor(pd[j], o, 64);
      }
    }
    if (col16 == 0) {
#pragma unroll
      for (int j = 0; j < 4; ++j) {
        peL[q][rbase + j] = pe[j];
        pdL[q][rbase + j] = pd[j];
      }
    }
    __syncthreads();
    if (tid < 32) {
      esW[rowbase + tid] = peL[0][tid] + peL[1][tid] + peL[2][tid] + peL[3][tid];
    } else if (tid < 64) {
      int r_ = tid - 32;
      edW[rowbase + r_] = pdL[0][r_] + pdL[1][r_] + pdL[2][r_] + pdL[3][r_];
    }
  } else {
    // ---- G4: out = h @ oW + ob (waves 0 and 4; 1 M-tile each) ----
    if (q == 0) {
      f32x4 acc4 = {0, 0, 0, 0};
#pragma unroll
      for (int kk = 0; kk < 2; ++kk) {
        f16x8 a = *(const f16x8*)&sx[m * 16 + col16][kk * 32 + afk];
        f16x8 bf = W4v[kk * 64 + lane];
        acc4 = __builtin_amdgcn_mfma_f32_16x16x32_f16(a, bf, acc4, 0, 0, 0);
      }
      if (col16 < 3) {
        float obv = ob[col16];
#pragma unroll
        for (int j = 0; j < 4; ++j) {
          int row = m * 16 + g4 + j;
          out[(size_t)(rowbase + row) * 3 + col16] = acc4[j] + obv;
        }
      }
    }
  }
}

extern "C" void kernel_launch(void* const* d_in, const int* in_sizes, int n_in,
                              void* d_out, int out_size, void* d_ws, size_t ws_size,
                              hipStream_t stream) {
  const float* x = (const float*)d_in[0];
  const int* src = (const int*)d_in[1];
  const int* dst = (const int*)d_in[2];
  const float* gatW = (const float*)d_in[3];
  const float* asrc = (const float*)d_in[4];
  const float* adst = (const float*)d_in[5];
  const float* gatb = (const float*)d_in[6];
  const float* g1W = (const float*)d_in[7];
  const float* g1b = (const float*)d_in[8];
  const float* g2W = (const float*)d_in[9];
  const float* g2b = (const float*)d_in[10];
  const float* oW = (const float*)d_in[11];
  const float* ob = (const float*)d_in[12];
  float* ws = (float*)d_ws;
  float* out = (float*)d_out;
  f16_t* P = (f16_t*)(ws + OFF_W);

  hipMemsetAsync(ws + OFF_CNT, 0, NN * sizeof(int), stream);
  k_prolog<<<PB_CONV + PB_FILL + PB_PACK + PB_GAT, 256, 0, stream>>>(
      x, src, dst, g1W, g2W, gatW, oW, asrc, adst, ws);
  for (int t = 0; t < TT; ++t) {
    k_step<<<BN / 32, 512, 0, stream>>>(ws, P, gatb, g1b, g2b, asrc, adst,
                                        ob, out, t, t == TT - 1 ? 1 : 0);
  }
}